// Round 5
// baseline (438.062 us; speedup 1.0000x reference)
//
#include <hip/hip_runtime.h>
#include <hip/hip_bf16.h>

typedef short bf16x8 __attribute__((ext_vector_type(8)));
typedef float f32x16 __attribute__((ext_vector_type(16)));

#define B_ 2
#define C_ 64
#define L_ 16
#define N_ 32
#define HW_ 4096

// ---- ws byte layout ----
#define BY_WPH   0u          // packed weights hi: 25088 frags * 16B = 401408
#define BY_WPL   401408u
#define BY_LR    802816u
#define BY_LI    811008u
#define BY_GM    819200u
#define BY_PART  827392u     // gn partial sums: 256 blocks * 8 f32
#define BY_WOT   835584u     // W_outT 64*64 f32
#define BY_XHI   851968u     // x bf16 plane [n][pix][ic] = 16777216
#define BY_U     851968u     // u f32 [n][pix][c] = 33554432 (aliases XHI, used after conv)

__device__ __forceinline__ unsigned short f2bf(float v) {
    unsigned int u = __float_as_uint(v);
    unsigned int r = u + 0x7FFFu + ((u >> 16) & 1u);
    return (unsigned short)(r >> 16);
}
__device__ __forceinline__ float bf2f(unsigned short s) {
    return __uint_as_float(((unsigned int)s) << 16);
}

// ---------------- pack W_eff = W_dc @ W_sp into B-fragment layout, hi/lo ----------------
// frag idx = ((tap*2+nf)*4+ks)*64 + lane ; lane: oc=nf*32+(lane&31), ic=ks*16+(lane>>5)*8+e
__global__ void k_pack(const float* __restrict__ W_sp, const float* __restrict__ W_dc,
                       unsigned short* __restrict__ WpH, unsigned short* __restrict__ WpL) {
    int idx = blockIdx.x * 256 + threadIdx.x;
    if (idx >= 49 * 512) return;
    int lane = idx & 63;
    int ks   = (idx >> 6) & 3;
    int nf   = (idx >> 8) & 1;
    int tap  = idx >> 9;
    int oc   = nf * 32 + (lane & 31);
    int icb  = ks * 16 + (lane >> 5) * 8;
    unsigned short h8[8], l8[8];
    #pragma unroll
    for (int e = 0; e < 8; ++e) {
        int ic = icb + e;
        float s = 0.f;
        for (int c = 0; c < 64; ++c)
            s += W_dc[oc * 64 + c] * W_sp[(c * 64 + ic) * 49 + tap];
        unsigned short hb = f2bf(s);
        h8[e] = hb;
        l8[e] = f2bf(s - bf2f(hb));
    }
    #pragma unroll
    for (int e = 0; e < 8; ++e) { WpH[idx * 8 + e] = h8[e]; WpL[idx * 8 + e] = l8[e]; }
}

// ---------------- transpose W_out ----------------
__global__ void k_wot(const float* __restrict__ W_out, float* __restrict__ W_outT) {
    int idx = blockIdx.x * 256 + threadIdx.x;
    if (idx >= 64 * 64) return;
    int o = idx >> 6, j = idx & 63;
    W_outT[o * 64 + j] = W_out[j * 64 + o];
}

// ---------------- lambda tables ----------------
__global__ void k_lam(const float* __restrict__ dt, const float* __restrict__ nu_log,
                      const float* __restrict__ theta_log,
                      float* __restrict__ lr_t, float* __restrict__ li_t, float* __restrict__ gm_t) {
    int idx = blockIdx.x * 256 + threadIdx.x;
    if (idx >= N_ * C_) return;
    int c = idx & 63, n = idx >> 6;
    float dtv = dt[n];
    float decay = expf(-expf(nu_log[c]) * dtv);
    float phase = expf(theta_log[c]) * dtv;
    lr_t[idx] = decay * cosf(phase);
    li_t[idx] = decay * sinf(phase);
    gm_t[idx] = sqrtf(fmaxf(1.f - decay * decay, 1e-6f));
}

// ---------------- x transpose to bf16 plane: xhi[n][pix][ic] ----------------
__global__ __launch_bounds__(256) void k_tr(const float* __restrict__ x,
                                            unsigned short* __restrict__ xhi) {
    __shared__ float t[64][129];
    int n = blockIdx.x >> 2, q = blockIdx.x & 3;
    int b = n >> 4, l = n & 15;
    int tid = threadIdx.x;
    for (int sub = 0; sub < 8; ++sub) {
        int p0 = q * 1024 + sub * 128;
        for (int i = 0; i < 32; ++i) {
            int idx = i * 256 + tid;
            int ic = idx >> 7, p = idx & 127;
            t[ic][p] = x[(((size_t)(b * 64 + ic) * 16 + l)) * 4096 + p0 + p];
        }
        __syncthreads();
        for (int it = 0; it < 4; ++it) {
            int chunk = it * 256 + tid;
            int p = chunk >> 3, c0 = (chunk & 7) * 8;
            unsigned short h8[8];
            #pragma unroll
            for (int e = 0; e < 8; ++e) h8[e] = f2bf(t[c0 + e][p]);
            size_t off = ((size_t)(n * 4096 + p0 + p)) * 64 + c0;
            *(uint4*)&xhi[off] = *(uint4*)h8;
        }
        __syncthreads();
    }
}

// ---------------- MFMA implicit-GEMM 7x7 conv (x bf16, w split hi/lo) ----------------
// block: 16x16 spatial tile x 64 oc, 4 waves; ic split into 2 halves of 32 (31KB LDS)
__global__ __launch_bounds__(256, 4) void k_conv(
    const unsigned short* __restrict__ xhi,
    const unsigned short* __restrict__ WpH, const unsigned short* __restrict__ WpL,
    const float* __restrict__ b_dc, float* __restrict__ y) {
    __shared__ __align__(16) char halo[484 * 64];   // 30976 B
    int tid = threadIdx.x;
    int tile = blockIdx.x;
    int th = tile >> 2, tw = tile & 3;
    int n = blockIdx.y;
    int lane = tid & 63, wid = tid >> 6;
    int dh = (lane >> 4) & 1, dw = lane & 15, kslot = lane >> 5;

    f32x16 acc[2][2] = {};

    for (int hf = 0; hf < 2; ++hf) {
        if (hf) __syncthreads();     // drain half-0 reads before restage
        // ---- stage half: 484 rows x 32 ic bf16 (64B rows), XOR-swizzled 16B slots
        for (int pass = wid; pass < 31; pass += 4) {
            int row = pass * 16 + (lane >> 2);
            if (row < 484) {
                int hh = row / 22, ww = row - hh * 22;
                int hs = th * 16 + hh - 3; hs = hs < 0 ? 0 : (hs > 63 ? 63 : hs);
                int wv = (tw * 16 + ww - 3) & 63;
                const uint4* src = (const uint4*)(xhi + ((size_t)n * 4096 + hs * 64 + wv) * 64 + hf * 32) + (lane & 3);
                uint4 v = *src;
                int q = (lane & 3) ^ (row & 3) ^ ((row >> 2) & 3);
                *(uint4*)(halo + row * 64 + q * 16) = v;
            }
        }
        __syncthreads();

        // ---- 49 taps, K=32 (2 ks-slices) per half
        for (int kh = 0; kh < 7; ++kh) {
            #pragma unroll
            for (int kw = 0; kw < 7; ++kw) {
                int tap = kh * 7 + kw;
                bf16x8 A[2][2];
                #pragma unroll
                for (int m = 0; m < 2; ++m) {
                    int rowb = (wid * 4 + 2 * m + dh + kh) * 22 + dw + kw;
                    int f = (rowb & 3) ^ ((rowb >> 2) & 3);
                    #pragma unroll
                    for (int ks = 0; ks < 2; ++ks) {
                        int q = (2 * ks + kslot) ^ f;
                        A[m][ks] = *(const bf16x8*)(halo + rowb * 64 + q * 16);
                    }
                }
                const bf16x8* WH = (const bf16x8*)WpH + (size_t)tap * 512 + lane;
                const bf16x8* WL = (const bf16x8*)WpL + (size_t)tap * 512 + lane;
                bf16x8 Bh[2][2], Bl[2][2];
                #pragma unroll
                for (int nf = 0; nf < 2; ++nf)
                    #pragma unroll
                    for (int ks = 0; ks < 2; ++ks) {
                        Bh[nf][ks] = WH[(nf * 4 + hf * 2 + ks) * 64];
                        Bl[nf][ks] = WL[(nf * 4 + hf * 2 + ks) * 64];
                    }
                #pragma unroll
                for (int ks = 0; ks < 2; ++ks)
                    #pragma unroll
                    for (int m = 0; m < 2; ++m)
                        #pragma unroll
                        for (int nf = 0; nf < 2; ++nf) {
                            acc[m][nf] = __builtin_amdgcn_mfma_f32_32x32x16_bf16(A[m][ks], Bh[nf][ks], acc[m][nf], 0, 0, 0);
                            acc[m][nf] = __builtin_amdgcn_mfma_f32_32x32x16_bf16(A[m][ks], Bl[nf][ks], acc[m][nf], 0, 0, 0);
                        }
            }
        }
    }

    // epilogue: C/D layout col=lane&31 (oc), row=(j&3)+8*(j>>2)+4*(lane>>5) (pixel)
    int ocl = lane & 31;
    #pragma unroll
    for (int nf = 0; nf < 2; ++nf) {
        float bv = b_dc[nf * 32 + ocl];
        #pragma unroll
        for (int m = 0; m < 2; ++m) {
            #pragma unroll
            for (int j = 0; j < 16; ++j) {
                int r = (j & 3) + 8 * (j >> 2) + 4 * (lane >> 5);
                int h = th * 16 + wid * 4 + 2 * m + (r >> 4);
                int w = tw * 16 + (r & 15);
                y[((size_t)n * 4096 + h * 64 + w) * 64 + nf * 32 + ocl] = acc[m][nf][j] + bv;
            }
        }
    }
}

// ---------------- GroupNorm partial sums per (n, chunk of 512 pixels) ----------------
__global__ __launch_bounds__(256) void k_gnstats(const float* __restrict__ y,
                                                 float* __restrict__ part) {
    int bid = blockIdx.x;          // n*8 + chunk
    int n = bid >> 3, chunk = bid & 7;
    int tid = threadIdx.x;
    int c4 = tid & 15, pl = tid >> 4;
    int g = c4 >> 2;
    float s = 0.f, s2 = 0.f;
    for (int i = 0; i < 32; ++i) {
        int p = chunk * 512 + i * 16 + pl;
        float4 v = *(const float4*)&y[((size_t)n * 4096 + p) * 64 + c4 * 4];
        s  += v.x + v.y + v.z + v.w;
        s2 += v.x * v.x + v.y * v.y + v.z * v.z + v.w * v.w;
    }
    __shared__ float rs[256], rq[256];
    int slot = g * 64 + pl * 4 + (c4 & 3);
    rs[slot] = s; rq[slot] = s2;
    __syncthreads();
    for (int off = 32; off >= 1; off >>= 1) {
        int g2 = tid >> 6, k = tid & 63;
        if (k < off) {
            rs[g2 * 64 + k] += rs[g2 * 64 + k + off];
            rq[g2 * 64 + k] += rq[g2 * 64 + k + off];
        }
        __syncthreads();
    }
    if (tid < 4) {
        part[bid * 8 + tid * 2]     = rs[tid * 64];
        part[bid * 8 + tid * 2 + 1] = rq[tid * 64];
    }
}

// ---------------- GN-apply + W_in + GLU + W_out + residual ----------------
// launch_bounds(256,1): forbid spilling of yn[64]+uacc[64]; 8-chain ILP dot products.
__global__ __launch_bounds__(256, 1) void k_pw(
    const float* __restrict__ y, const float* __restrict__ part,
    const float* __restrict__ gn_g, const float* __restrict__ gn_b,
    const float* __restrict__ W_in, const float* __restrict__ b_in,
    const float* __restrict__ W_outT, const float* __restrict__ b_out,
    const float* __restrict__ x, float* __restrict__ u) {
    int gidx = blockIdx.x * 256 + threadIdx.x;
    int n = gidx >> 12;
    int pix = gidx & 4095;
    int b = n >> 4, l = n & 15;

    float yn[64];
    const float* yrow = &y[(size_t)(n * 4096 + pix) * 64];
    #pragma unroll
    for (int c4 = 0; c4 < 16; ++c4) {
        float4 v = *(const float4*)&yrow[c4 * 4];
        yn[c4 * 4 + 0] = v.x; yn[c4 * 4 + 1] = v.y;
        yn[c4 * 4 + 2] = v.z; yn[c4 * 4 + 3] = v.w;
    }
    #pragma unroll
    for (int gg = 0; gg < 4; ++gg) {
        float sm = 0.f, sq = 0.f;
        #pragma unroll
        for (int ch = 0; ch < 8; ++ch) {
            sm += part[(n * 8 + ch) * 8 + gg * 2];
            sq += part[(n * 8 + ch) * 8 + gg * 2 + 1];
        }
        float mean = sm * (1.f / 65536.f);
        float var  = sq * (1.f / 65536.f) - mean * mean;
        float rstd = rsqrtf(var + 1e-5f);
        #pragma unroll
        for (int k = 0; k < 16; ++k) {
            int c = gg * 16 + k;
            yn[c] = (yn[c] - mean) * rstd * gn_g[c] + gn_b[c];
        }
    }
    float uacc[64];
    #pragma unroll
    for (int j = 0; j < 64; ++j) uacc[j] = b_out[j];

    for (int o = 0; o < 64; o += 2) {
        const float* w1a = &W_in[o * 64];
        const float* w2a = &W_in[(64 + o) * 64];
        const float* w1b = &W_in[(o + 1) * 64];
        const float* w2b = &W_in[(64 + o + 1) * 64];
        float a10 = 0.f, a11 = 0.f, a20 = 0.f, a21 = 0.f;
        float b10 = 0.f, b11 = 0.f, b20 = 0.f, b21 = 0.f;
        #pragma unroll
        for (int c = 0; c < 64; c += 2) {
            float y0 = yn[c], y1 = yn[c + 1];
            a10 += y0 * w1a[c]; a11 += y1 * w1a[c + 1];
            a20 += y0 * w2a[c]; a21 += y1 * w2a[c + 1];
            b10 += y0 * w1b[c]; b11 += y1 * w1b[c + 1];
            b20 += y0 * w2b[c]; b21 += y1 * w2b[c + 1];
        }
        float x1A = a10 + a11 + b_in[o];
        float x2A = a20 + a21 + b_in[64 + o];
        float x1B = b10 + b11 + b_in[o + 1];
        float x2B = b20 + b21 + b_in[64 + o + 1];
        float zA = x1A / (1.f + __expf(-x2A));
        float zB = x1B / (1.f + __expf(-x2B));
        const float* woA = &W_outT[o * 64];
        const float* woB = &W_outT[(o + 1) * 64];
        #pragma unroll
        for (int j = 0; j < 64; ++j)
            uacc[j] += zA * woA[j] + zB * woB[j];
    }
    #pragma unroll
    for (int j = 0; j < 64; ++j)
        uacc[j] += x[((size_t)(b * 64 + j) * 16 + l) * 4096 + pix];

    float* urow = &u[(size_t)(n * 4096 + pix) * 64];
    #pragma unroll
    for (int j4 = 0; j4 < 16; ++j4) {
        float4 st;
        st.x = uacc[j4 * 4 + 0]; st.y = uacc[j4 * 4 + 1];
        st.z = uacc[j4 * 4 + 2]; st.w = uacc[j4 * 4 + 3];
        *(float4*)&urow[j4 * 4] = st;
    }
}

// ---------------- LRU scan: 512 blocks = (b, h, wq), coalesced float4 reads ----------------
__global__ __launch_bounds__(256) void k_scan(
    const float* __restrict__ u, const float* __restrict__ lr_t,
    const float* __restrict__ li_t, const float* __restrict__ gm_t,
    const float* __restrict__ c_re, const float* __restrict__ c_im,
    const float* __restrict__ d_skip, float* __restrict__ out) {
    __shared__ float us[16][68];
    int tid = threadIdx.x;
    int bid = blockIdx.x;
    int b = bid >> 8, h = (bid >> 2) & 63, wq = bid & 3;
    int c4 = tid & 15, p = tid >> 4;        // compute mapping: c_base = c4*4, w = wq*16+p
    int w = wq * 16 + p;
    float4 cr4 = *(const float4*)&c_re[c4 * 4];
    float4 ci4 = *(const float4*)&c_im[c4 * 4];
    float4 ds4 = *(const float4*)&d_skip[c4 * 4];
    float hr[4] = {}, hi[4] = {};
    int wp = tid & 15, cc = tid >> 4;       // write mapping
    for (int l = 0; l < 16; ++l) {
        int n = b * 16 + l;
        float4 uv = *(const float4*)&u[((size_t)(n * 4096 + h * 64 + w)) * 64 + c4 * 4];
        float4 lr4 = *(const float4*)&lr_t[n * 64 + c4 * 4];
        float4 li4 = *(const float4*)&li_t[n * 64 + c4 * 4];
        float4 gm4 = *(const float4*)&gm_t[n * 64 + c4 * 4];
        float yv[4];
        {
            float ut = uv.x, lr = lr4.x, li = li4.x;
            float nr = lr * hr[0] - li * hi[0] + gm4.x * ut;
            float ni = li * hr[0] + lr * hi[0];
            yv[0] = cr4.x * nr + ci4.x * ni + ds4.x * ut; hr[0] = nr; hi[0] = ni;
        }
        {
            float ut = uv.y, lr = lr4.y, li = li4.y;
            float nr = lr * hr[1] - li * hi[1] + gm4.y * ut;
            float ni = li * hr[1] + lr * hi[1];
            yv[1] = cr4.y * nr + ci4.y * ni + ds4.y * ut; hr[1] = nr; hi[1] = ni;
        }
        {
            float ut = uv.z, lr = lr4.z, li = li4.z;
            float nr = lr * hr[2] - li * hi[2] + gm4.z * ut;
            float ni = li * hr[2] + lr * hi[2];
            yv[2] = cr4.z * nr + ci4.z * ni + ds4.z * ut; hr[2] = nr; hi[2] = ni;
        }
        {
            float ut = uv.w, lr = lr4.w, li = li4.w;
            float nr = lr * hr[3] - li * hi[3] + gm4.w * ut;
            float ni = li * hr[3] + lr * hi[3];
            yv[3] = cr4.w * nr + ci4.w * ni + ds4.w * ut; hr[3] = nr; hi[3] = ni;
        }
        *(float4*)&us[p][c4 * 4] = *(float4*)yv;
        __syncthreads();
        #pragma unroll
        for (int j = 0; j < 4; ++j) {
            int c = cc * 4 + j;
            out[((size_t)(b * 64 + c) * 16 + l) * 4096 + h * 64 + wq * 16 + wp] = us[wp][c];
        }
        __syncthreads();
    }
}

extern "C" void kernel_launch(void* const* d_in, const int* in_sizes, int n_in,
                              void* d_out, int out_size, void* d_ws, size_t ws_size,
                              hipStream_t stream) {
    const float* x        = (const float*)d_in[0];
    const float* dt       = (const float*)d_in[1];
    const float* W_sp     = (const float*)d_in[2];
    const float* W_dc     = (const float*)d_in[3];
    const float* b_dc     = (const float*)d_in[4];
    const float* gn_g     = (const float*)d_in[5];
    const float* gn_b     = (const float*)d_in[6];
    const float* W_in     = (const float*)d_in[7];
    const float* b_in     = (const float*)d_in[8];
    const float* W_out    = (const float*)d_in[9];
    const float* b_out    = (const float*)d_in[10];
    const float* nu_log   = (const float*)d_in[11];
    const float* theta_log= (const float*)d_in[12];
    const float* c_re     = (const float*)d_in[13];
    const float* c_im     = (const float*)d_in[14];
    const float* d_skip   = (const float*)d_in[15];

    char* ws = (char*)d_ws;
    unsigned short* WpH  = (unsigned short*)(ws + BY_WPH);
    unsigned short* WpL  = (unsigned short*)(ws + BY_WPL);
    float* lr_t   = (float*)(ws + BY_LR);
    float* li_t   = (float*)(ws + BY_LI);
    float* gm_t   = (float*)(ws + BY_GM);
    float* part   = (float*)(ws + BY_PART);
    float* W_outT = (float*)(ws + BY_WOT);
    unsigned short* xhi = (unsigned short*)(ws + BY_XHI);
    float* u      = (float*)(ws + BY_U);
    float* y      = (float*)d_out;     // y lives in d_out until k_pw consumes it
    float* out    = (float*)d_out;

    hipLaunchKernelGGL(k_pack,    dim3(98),        dim3(256), 0, stream, W_sp, W_dc, WpH, WpL);
    hipLaunchKernelGGL(k_wot,     dim3(16),        dim3(256), 0, stream, W_out, W_outT);
    hipLaunchKernelGGL(k_lam,     dim3(8),         dim3(256), 0, stream, dt, nu_log, theta_log, lr_t, li_t, gm_t);
    hipLaunchKernelGGL(k_tr,      dim3(128),       dim3(256), 0, stream, x, xhi);
    hipLaunchKernelGGL(k_conv,    dim3(16, 32),    dim3(256), 0, stream, xhi, WpH, WpL, b_dc, y);
    hipLaunchKernelGGL(k_gnstats, dim3(256),       dim3(256), 0, stream, y, part);
    hipLaunchKernelGGL(k_pw,      dim3(512),       dim3(256), 0, stream, y, part, gn_g, gn_b,
                       W_in, b_in, W_outT, b_out, x, u);
    hipLaunchKernelGGL(k_scan,    dim3(512),       dim3(256), 0, stream, u, lr_t, li_t, gm_t,
                       c_re, c_im, d_skip, out);
}

// Round 6
// 259.545 us; speedup vs baseline: 1.6878x; 1.6878x over previous
//
#include <hip/hip_runtime.h>
#include <hip/hip_bf16.h>

typedef short bf16x8 __attribute__((ext_vector_type(8)));
typedef float f32x16 __attribute__((ext_vector_type(16)));

#define B_ 2
#define C_ 64
#define L_ 16
#define N_ 32
#define HW_ 4096

// ---- ws byte layout ----
#define BY_WPH   0u          // packed weights hi: 25088 frags * 16B = 401408
#define BY_WPL   401408u     // (kept for layout stability; unused by k_conv now)
#define BY_LR    802816u
#define BY_LI    811008u
#define BY_GM    819200u
#define BY_PART  827392u     // gn partial sums: 256 blocks * 8 f32
#define BY_WOT   835584u     // W_outT 64*64 f32
#define BY_XHI   851968u     // x bf16 plane [n][pix][ic] = 16777216
#define BY_U     851968u     // u f32 [n][pix][c] = 33554432 (aliases XHI, used after conv)

__device__ __forceinline__ unsigned short f2bf(float v) {
    unsigned int u = __float_as_uint(v);
    unsigned int r = u + 0x7FFFu + ((u >> 16) & 1u);
    return (unsigned short)(r >> 16);
}
__device__ __forceinline__ float bf2f(unsigned short s) {
    return __uint_as_float(((unsigned int)s) << 16);
}

// ---------------- pack W_eff = W_dc @ W_sp into B-fragment layout ----------------
// frag idx = ((tap*2+nf)*4+ks)*64 + lane ; lane: oc=nf*32+(lane&31), ic=ks*16+(lane>>5)*8+e
__global__ void k_pack(const float* __restrict__ W_sp, const float* __restrict__ W_dc,
                       unsigned short* __restrict__ WpH) {
    int idx = blockIdx.x * 256 + threadIdx.x;
    if (idx >= 49 * 512) return;
    int lane = idx & 63;
    int ks   = (idx >> 6) & 3;
    int nf   = (idx >> 8) & 1;
    int tap  = idx >> 9;
    int oc   = nf * 32 + (lane & 31);
    int icb  = ks * 16 + (lane >> 5) * 8;
    unsigned short h8[8];
    #pragma unroll
    for (int e = 0; e < 8; ++e) {
        int ic = icb + e;
        float s = 0.f;
        for (int c = 0; c < 64; ++c)
            s += W_dc[oc * 64 + c] * W_sp[(c * 64 + ic) * 49 + tap];
        h8[e] = f2bf(s);
    }
    #pragma unroll
    for (int e = 0; e < 8; ++e) WpH[idx * 8 + e] = h8[e];
}

// ---------------- transpose W_out ----------------
__global__ void k_wot(const float* __restrict__ W_out, float* __restrict__ W_outT) {
    int idx = blockIdx.x * 256 + threadIdx.x;
    if (idx >= 64 * 64) return;
    int o = idx >> 6, j = idx & 63;
    W_outT[o * 64 + j] = W_out[j * 64 + o];
}

// ---------------- lambda tables ----------------
__global__ void k_lam(const float* __restrict__ dt, const float* __restrict__ nu_log,
                      const float* __restrict__ theta_log,
                      float* __restrict__ lr_t, float* __restrict__ li_t, float* __restrict__ gm_t) {
    int idx = blockIdx.x * 256 + threadIdx.x;
    if (idx >= N_ * C_) return;
    int c = idx & 63, n = idx >> 6;
    float dtv = dt[n];
    float decay = expf(-expf(nu_log[c]) * dtv);
    float phase = expf(theta_log[c]) * dtv;
    lr_t[idx] = decay * cosf(phase);
    li_t[idx] = decay * sinf(phase);
    gm_t[idx] = sqrtf(fmaxf(1.f - decay * decay, 1e-6f));
}

// ---------------- x transpose to bf16 plane: xhi[n][pix][ic] ----------------
__global__ __launch_bounds__(256) void k_tr(const float* __restrict__ x,
                                            unsigned short* __restrict__ xhi) {
    __shared__ float t[64][129];
    int n = blockIdx.x >> 2, q = blockIdx.x & 3;
    int b = n >> 4, l = n & 15;
    int tid = threadIdx.x;
    for (int sub = 0; sub < 8; ++sub) {
        int p0 = q * 1024 + sub * 128;
        for (int i = 0; i < 32; ++i) {
            int idx = i * 256 + tid;
            int ic = idx >> 7, p = idx & 127;
            t[ic][p] = x[(((size_t)(b * 64 + ic) * 16 + l)) * 4096 + p0 + p];
        }
        __syncthreads();
        for (int it = 0; it < 4; ++it) {
            int chunk = it * 256 + tid;
            int p = chunk >> 3, c0 = (chunk & 7) * 8;
            unsigned short h8[8];
            #pragma unroll
            for (int e = 0; e < 8; ++e) h8[e] = f2bf(t[c0 + e][p]);
            size_t off = ((size_t)(n * 4096 + p0 + p)) * 64 + c0;
            *(uint4*)&xhi[off] = *(uint4*)h8;
        }
        __syncthreads();
    }
}

// ---------------- MFMA implicit-GEMM 7x7 conv (x bf16, w bf16, B-prefetch) ----------------
// block: 16x16 spatial tile x 64 oc, 4 waves (each 64 pix x 64 oc = 2x2 of 32x32 frags)
__global__ __launch_bounds__(256, 2) void k_conv(
    const unsigned short* __restrict__ xhi,
    const unsigned short* __restrict__ WpH,
    const float* __restrict__ b_dc, float* __restrict__ y) {
    __shared__ uint4 halo[3904];   // 484 rows x 128B (+pad)
    int tid = threadIdx.x;
    int tile = blockIdx.x;
    int th = tile >> 2, tw = tile & 3;
    int n = blockIdx.y;
    int lane = tid & 63, wid = tid >> 6;
    int dh = (lane >> 4) & 1, dw = lane & 15, kslot = lane >> 5;

    // ---- stage halo plane (484 rows of 64 ic bf16, 16B-slot XOR swizzle)
    for (int u2 = wid; u2 < 61; u2 += 4) {
        int row = u2 * 8 + (lane >> 3);
        if (row > 483) row = 483;
        int hh = row / 22, ww = row - hh * 22;
        int hs = th * 16 + hh - 3; hs = hs < 0 ? 0 : (hs > 63 ? 63 : hs);
        int wv = (tw * 16 + ww - 3) & 63;
        const uint4* src = (const uint4*)(xhi + ((size_t)n * 4096 + hs * 64 + wv) * 64) + (lane & 7);
        uint4 v = *src;
        *(uint4*)((char*)halo + ((row << 7) + (((lane & 7) ^ (row & 7)) << 4))) = v;
    }
    __syncthreads();

    f32x16 acc[2][2] = {};
    bf16x8 Ba[2][4], Bb[2][4];

#define LOADB(Breg, tap) { \
    const bf16x8* WH = (const bf16x8*)WpH + (size_t)(tap) * 512 + lane; \
    _Pragma("unroll") for (int nf = 0; nf < 2; ++nf) \
        _Pragma("unroll") for (int ks = 0; ks < 4; ++ks) \
            Breg[nf][ks] = WH[(nf * 4 + ks) * 64]; }

#define COMPUTE(khv, kwv, Breg) { \
    bf16x8 A[2][4]; \
    _Pragma("unroll") for (int m = 0; m < 2; ++m) { \
        int rowb = (wid * 4 + 2 * m + dh + (khv)) * 22 + dw + (kwv); \
        _Pragma("unroll") for (int ks = 0; ks < 4; ++ks) { \
            int byt = (rowb << 7) + (((2 * ks + kslot) ^ (rowb & 7)) << 4); \
            A[m][ks] = *(const bf16x8*)((const char*)halo + byt); } } \
    _Pragma("unroll") for (int ks = 0; ks < 4; ++ks) \
        _Pragma("unroll") for (int m = 0; m < 2; ++m) \
            _Pragma("unroll") for (int nf = 0; nf < 2; ++nf) \
                acc[m][nf] = __builtin_amdgcn_mfma_f32_32x32x16_bf16(A[m][ks], Breg[nf][ks], acc[m][nf], 0, 0, 0); }

    LOADB(Ba, 0);
    int kh = 0, kw = 0;
    for (int t = 0; t < 48; t += 2) {
        LOADB(Bb, t + 1);
        COMPUTE(kh, kw, Ba);
        ++kw; if (kw == 7) { kw = 0; ++kh; }
        LOADB(Ba, t + 2);
        COMPUTE(kh, kw, Bb);
        ++kw; if (kw == 7) { kw = 0; ++kh; }
    }
    COMPUTE(kh, kw, Ba);
#undef LOADB
#undef COMPUTE

    // epilogue: C/D layout col=lane&31 (oc), row=(j&3)+8*(j>>2)+4*(lane>>5) (pixel)
    int ocl = lane & 31;
    #pragma unroll
    for (int nf = 0; nf < 2; ++nf) {
        float bv = b_dc[nf * 32 + ocl];
        #pragma unroll
        for (int m = 0; m < 2; ++m) {
            #pragma unroll
            for (int j = 0; j < 16; ++j) {
                int r = (j & 3) + 8 * (j >> 2) + 4 * (lane >> 5);
                int h = th * 16 + wid * 4 + 2 * m + (r >> 4);
                int w = tw * 16 + (r & 15);
                y[((size_t)n * 4096 + h * 64 + w) * 64 + nf * 32 + ocl] = acc[m][nf][j] + bv;
            }
        }
    }
}

// ---------------- GroupNorm partial sums per (n, chunk of 512 pixels) ----------------
__global__ __launch_bounds__(256) void k_gnstats(const float* __restrict__ y,
                                                 float* __restrict__ part) {
    int bid = blockIdx.x;          // n*8 + chunk
    int n = bid >> 3, chunk = bid & 7;
    int tid = threadIdx.x;
    int c4 = tid & 15, pl = tid >> 4;
    int g = c4 >> 2;
    float s = 0.f, s2 = 0.f;
    for (int i = 0; i < 32; ++i) {
        int p = chunk * 512 + i * 16 + pl;
        float4 v = *(const float4*)&y[((size_t)n * 4096 + p) * 64 + c4 * 4];
        s  += v.x + v.y + v.z + v.w;
        s2 += v.x * v.x + v.y * v.y + v.z * v.z + v.w * v.w;
    }
    __shared__ float rs[256], rq[256];
    int slot = g * 64 + pl * 4 + (c4 & 3);
    rs[slot] = s; rq[slot] = s2;
    __syncthreads();
    for (int off = 32; off >= 1; off >>= 1) {
        int g2 = tid >> 6, k = tid & 63;
        if (k < off) {
            rs[g2 * 64 + k] += rs[g2 * 64 + k + off];
            rq[g2 * 64 + k] += rq[g2 * 64 + k + off];
        }
        __syncthreads();
    }
    if (tid < 4) {
        part[bid * 8 + tid * 2]     = rs[tid * 64];
        part[bid * 8 + tid * 2 + 1] = rq[tid * 64];
    }
}

// ---------------- GN-apply + W_in + GLU + W_out + residual ----------------
// Per-wave LDS panel (XOR-swizzled 16B slots) for fully-coalesced global I/O.
__global__ __launch_bounds__(256, 1) void k_pw(
    const float* __restrict__ y, const float* __restrict__ part,
    const float* __restrict__ gn_g, const float* __restrict__ gn_b,
    const float* __restrict__ W_in, const float* __restrict__ b_in,
    const float* __restrict__ W_outT, const float* __restrict__ b_out,
    const float* __restrict__ x, float* __restrict__ u) {
    __shared__ float pan[4][64][64];   // 64 KB, per-wave 16 KB panel
    int tid = threadIdx.x;
    int lane = tid & 63, wid = tid >> 6;
    int blk = blockIdx.x;
    int n = blk >> 4;                  // 16 blocks per n
    int pgrp = blk & 15;
    int b = n >> 4, l = n & 15;
    int pix = pgrp * 256 + wid * 64 + lane;

    // ---- coalesced load of wave's 64x64 y panel into LDS (swizzled slots)
    const float4* Y4 = (const float4*)(y + ((size_t)n * 4096 + pgrp * 256 + wid * 64) * 64);
    #pragma unroll
    for (int i = 0; i < 16; ++i) {
        int e = i * 64 + lane;
        float4 v = Y4[e];
        int row = e >> 4, c4 = e & 15;
        *(float4*)&pan[wid][row][(c4 ^ (row & 15)) * 4] = v;
    }
    __syncthreads();

    // ---- read own pixel row from LDS
    float yn[64];
    #pragma unroll
    for (int c4 = 0; c4 < 16; ++c4) {
        float4 v = *(const float4*)&pan[wid][lane][((c4 ^ (lane & 15))) * 4];
        yn[c4 * 4 + 0] = v.x; yn[c4 * 4 + 1] = v.y;
        yn[c4 * 4 + 2] = v.z; yn[c4 * 4 + 3] = v.w;
    }

    // ---- GN apply
    #pragma unroll
    for (int gg = 0; gg < 4; ++gg) {
        float sm = 0.f, sq = 0.f;
        #pragma unroll
        for (int ch = 0; ch < 8; ++ch) {
            sm += part[(n * 8 + ch) * 8 + gg * 2];
            sq += part[(n * 8 + ch) * 8 + gg * 2 + 1];
        }
        float mean = sm * (1.f / 65536.f);
        float var  = sq * (1.f / 65536.f) - mean * mean;
        float rstd = rsqrtf(var + 1e-5f);
        #pragma unroll
        for (int k = 0; k < 16; ++k) {
            int c = gg * 16 + k;
            yn[c] = (yn[c] - mean) * rstd * gn_g[c] + gn_b[c];
        }
    }

    float uacc[64];
    #pragma unroll
    for (int j = 0; j < 64; ++j) uacc[j] = b_out[j];

    for (int o = 0; o < 64; o += 2) {
        const float* w1a = &W_in[o * 64];
        const float* w2a = &W_in[(64 + o) * 64];
        const float* w1b = &W_in[(o + 1) * 64];
        const float* w2b = &W_in[(64 + o + 1) * 64];
        float a10 = 0.f, a11 = 0.f, a20 = 0.f, a21 = 0.f;
        float b10 = 0.f, b11 = 0.f, b20 = 0.f, b21 = 0.f;
        #pragma unroll
        for (int c = 0; c < 64; c += 2) {
            float y0 = yn[c], y1 = yn[c + 1];
            a10 += y0 * w1a[c]; a11 += y1 * w1a[c + 1];
            a20 += y0 * w2a[c]; a21 += y1 * w2a[c + 1];
            b10 += y0 * w1b[c]; b11 += y1 * w1b[c + 1];
            b20 += y0 * w2b[c]; b21 += y1 * w2b[c + 1];
        }
        float x1A = a10 + a11 + b_in[o];
        float x2A = a20 + a21 + b_in[64 + o];
        float x1B = b10 + b11 + b_in[o + 1];
        float x2B = b20 + b21 + b_in[64 + o + 1];
        float zA = x1A / (1.f + __expf(-x2A));
        float zB = x1B / (1.f + __expf(-x2B));
        const float* woA = &W_outT[o * 64];
        const float* woB = &W_outT[(o + 1) * 64];
        #pragma unroll
        for (int j = 0; j < 64; ++j)
            uacc[j] += zA * woA[j] + zB * woB[j];
    }
    #pragma unroll
    for (int j = 0; j < 64; ++j)
        uacc[j] += x[((size_t)(b * 64 + j) * 16 + l) * 4096 + pix];

    __syncthreads();
    // ---- write own row to LDS (swizzled), then coalesced global store
    #pragma unroll
    for (int j4 = 0; j4 < 16; ++j4) {
        float4 st;
        st.x = uacc[j4 * 4 + 0]; st.y = uacc[j4 * 4 + 1];
        st.z = uacc[j4 * 4 + 2]; st.w = uacc[j4 * 4 + 3];
        *(float4*)&pan[wid][lane][((j4 ^ (lane & 15))) * 4] = st;
    }
    __syncthreads();
    float4* U4 = (float4*)(u + ((size_t)n * 4096 + pgrp * 256 + wid * 64) * 64);
    #pragma unroll
    for (int i = 0; i < 16; ++i) {
        int e = i * 64 + lane;
        int row = e >> 4, c4 = e & 15;
        U4[e] = *(const float4*)&pan[wid][row][((c4 ^ (row & 15))) * 4];
    }
}

// ---------------- LRU scan: 512 blocks = (b, h, wq), coalesced float4 reads ----------------
__global__ __launch_bounds__(256) void k_scan(
    const float* __restrict__ u, const float* __restrict__ lr_t,
    const float* __restrict__ li_t, const float* __restrict__ gm_t,
    const float* __restrict__ c_re, const float* __restrict__ c_im,
    const float* __restrict__ d_skip, float* __restrict__ out) {
    __shared__ float us[16][68];
    int tid = threadIdx.x;
    int bid = blockIdx.x;
    int b = bid >> 8, h = (bid >> 2) & 63, wq = bid & 3;
    int c4 = tid & 15, p = tid >> 4;
    int w = wq * 16 + p;
    float4 cr4 = *(const float4*)&c_re[c4 * 4];
    float4 ci4 = *(const float4*)&c_im[c4 * 4];
    float4 ds4 = *(const float4*)&d_skip[c4 * 4];
    float hr[4] = {}, hi[4] = {};
    int wp = tid & 15, cc = tid >> 4;
    for (int l = 0; l < 16; ++l) {
        int n = b * 16 + l;
        float4 uv = *(const float4*)&u[((size_t)(n * 4096 + h * 64 + w)) * 64 + c4 * 4];
        float4 lr4 = *(const float4*)&lr_t[n * 64 + c4 * 4];
        float4 li4 = *(const float4*)&li_t[n * 64 + c4 * 4];
        float4 gm4 = *(const float4*)&gm_t[n * 64 + c4 * 4];
        float yv[4];
        {
            float ut = uv.x, lr = lr4.x, li = li4.x;
            float nr = lr * hr[0] - li * hi[0] + gm4.x * ut;
            float ni = li * hr[0] + lr * hi[0];
            yv[0] = cr4.x * nr + ci4.x * ni + ds4.x * ut; hr[0] = nr; hi[0] = ni;
        }
        {
            float ut = uv.y, lr = lr4.y, li = li4.y;
            float nr = lr * hr[1] - li * hi[1] + gm4.y * ut;
            float ni = li * hr[1] + lr * hi[1];
            yv[1] = cr4.y * nr + ci4.y * ni + ds4.y * ut; hr[1] = nr; hi[1] = ni;
        }
        {
            float ut = uv.z, lr = lr4.z, li = li4.z;
            float nr = lr * hr[2] - li * hi[2] + gm4.z * ut;
            float ni = li * hr[2] + lr * hi[2];
            yv[2] = cr4.z * nr + ci4.z * ni + ds4.z * ut; hr[2] = nr; hi[2] = ni;
        }
        {
            float ut = uv.w, lr = lr4.w, li = li4.w;
            float nr = lr * hr[3] - li * hi[3] + gm4.w * ut;
            float ni = li * hr[3] + lr * hi[3];
            yv[3] = cr4.w * nr + ci4.w * ni + ds4.w * ut; hr[3] = nr; hi[3] = ni;
        }
        *(float4*)&us[p][c4 * 4] = *(float4*)yv;
        __syncthreads();
        #pragma unroll
        for (int j = 0; j < 4; ++j) {
            int c = cc * 4 + j;
            out[((size_t)(b * 64 + c) * 16 + l) * 4096 + h * 64 + wq * 16 + wp] = us[wp][c];
        }
        __syncthreads();
    }
}

extern "C" void kernel_launch(void* const* d_in, const int* in_sizes, int n_in,
                              void* d_out, int out_size, void* d_ws, size_t ws_size,
                              hipStream_t stream) {
    const float* x        = (const float*)d_in[0];
    const float* dt       = (const float*)d_in[1];
    const float* W_sp     = (const float*)d_in[2];
    const float* W_dc     = (const float*)d_in[3];
    const float* b_dc     = (const float*)d_in[4];
    const float* gn_g     = (const float*)d_in[5];
    const float* gn_b     = (const float*)d_in[6];
    const float* W_in     = (const float*)d_in[7];
    const float* b_in     = (const float*)d_in[8];
    const float* W_out    = (const float*)d_in[9];
    const float* b_out    = (const float*)d_in[10];
    const float* nu_log   = (const float*)d_in[11];
    const float* theta_log= (const float*)d_in[12];
    const float* c_re     = (const float*)d_in[13];
    const float* c_im     = (const float*)d_in[14];
    const float* d_skip   = (const float*)d_in[15];

    char* ws = (char*)d_ws;
    unsigned short* WpH  = (unsigned short*)(ws + BY_WPH);
    float* lr_t   = (float*)(ws + BY_LR);
    float* li_t   = (float*)(ws + BY_LI);
    float* gm_t   = (float*)(ws + BY_GM);
    float* part   = (float*)(ws + BY_PART);
    float* W_outT = (float*)(ws + BY_WOT);
    unsigned short* xhi = (unsigned short*)(ws + BY_XHI);
    float* u      = (float*)(ws + BY_U);
    float* y      = (float*)d_out;     // y lives in d_out until k_pw consumes it
    float* out    = (float*)d_out;

    hipLaunchKernelGGL(k_pack,    dim3(98),        dim3(256), 0, stream, W_sp, W_dc, WpH);
    hipLaunchKernelGGL(k_wot,     dim3(16),        dim3(256), 0, stream, W_out, W_outT);
    hipLaunchKernelGGL(k_lam,     dim3(8),         dim3(256), 0, stream, dt, nu_log, theta_log, lr_t, li_t, gm_t);
    hipLaunchKernelGGL(k_tr,      dim3(128),       dim3(256), 0, stream, x, xhi);
    hipLaunchKernelGGL(k_conv,    dim3(16, 32),    dim3(256), 0, stream, xhi, WpH, b_dc, y);
    hipLaunchKernelGGL(k_gnstats, dim3(256),       dim3(256), 0, stream, y, part);
    hipLaunchKernelGGL(k_pw,      dim3(512),       dim3(256), 0, stream, y, part, gn_g, gn_b,
                       W_in, b_in, W_outT, b_out, x, u);
    hipLaunchKernelGGL(k_scan,    dim3(512),       dim3(256), 0, stream, u, lr_t, li_t, gm_t,
                       c_re, c_im, d_skip, out);
}

// Round 7
// 155.520 us; speedup vs baseline: 2.8168x; 1.6689x over previous
//
#include <hip/hip_runtime.h>
#include <hip/hip_bf16.h>

typedef short bf16x8 __attribute__((ext_vector_type(8)));
typedef float f32x16 __attribute__((ext_vector_type(16)));

#define B_ 2
#define C_ 64
#define L_ 16
#define N_ 32
#define HW_ 4096

// ---- ws byte layout (end = 524288 + 33554432 = 34.1 MB < proven 35.2 MB) ----
#define BY_WPH  0u          // conv packed weights: 25088 frags * 16B = 401408
#define BY_WP1  401408u     // W_in' B-frags hi/lo: 2*16*64*16B = 32768
#define BY_WP2  434176u     // W_out B-frags hi/lo: 2*8*64*16B = 16384
#define BY_OFF1 450560u     // 128 f32
#define BY_LR   451072u
#define BY_LI   459264u
#define BY_GM   467456u
#define BY_PART 475648u     // 256 blocks * 8 f32
#define BY_XHI  524288u     // x bf16 plane [n][pix][ic] = 16777216 (dead after conv)
#define BY_U    524288u     // u f32 [n][pix][c] = 33554432 (aliases XHI)

__device__ __forceinline__ unsigned short f2bf(float v) {
    unsigned int u = __float_as_uint(v);
    unsigned int r = u + 0x7FFFu + ((u >> 16) & 1u);
    return (unsigned short)(r >> 16);
}
__device__ __forceinline__ float bf2f(unsigned short s) {
    return __uint_as_float(((unsigned int)s) << 16);
}

// ---------------- pack conv W_eff = W_dc @ W_sp into B-fragment layout ----------------
__global__ void k_pack(const float* __restrict__ W_sp, const float* __restrict__ W_dc,
                       unsigned short* __restrict__ WpH) {
    int idx = blockIdx.x * 256 + threadIdx.x;
    if (idx >= 49 * 512) return;
    int lane = idx & 63;
    int ks   = (idx >> 6) & 3;
    int nf   = (idx >> 8) & 1;
    int tap  = idx >> 9;
    int oc   = nf * 32 + (lane & 31);
    int icb  = ks * 16 + (lane >> 5) * 8;
    unsigned short h8[8];
    #pragma unroll
    for (int e = 0; e < 8; ++e) {
        int ic = icb + e;
        float s = 0.f;
        for (int c = 0; c < 64; ++c)
            s += W_dc[oc * 64 + c] * W_sp[(c * 64 + ic) * 49 + tap];
        h8[e] = f2bf(s);
    }
    #pragma unroll
    for (int e = 0; e < 8; ++e) WpH[idx * 8 + e] = h8[e];
}

// ---------------- pack pointwise weights: W_in*gn_g (hi/lo), W_out (hi/lo), off1 ----------------
// WP1 frag idx = hl*1024 + nf*256 + ks*64 + lane   (nf 0..3: cols o=nf*32.., K=c)
// WP2 frag idx = hl*512  + nf*256 + ks*64 + lane   (nf 0..1: cols j,       K=o)
__global__ void k_prep(const float* __restrict__ W_in, const float* __restrict__ b_in,
                       const float* __restrict__ W_out,
                       const float* __restrict__ gn_g, const float* __restrict__ gn_b,
                       unsigned short* __restrict__ WP1, unsigned short* __restrict__ WP2,
                       float* __restrict__ OFF1) {
    int idx = blockIdx.x * 256 + threadIdx.x;
    if (idx < 2048) {
        int lane = idx & 63, ks = (idx >> 6) & 3, nf = (idx >> 8) & 3, hl = idx >> 10;
        int o = nf * 32 + (lane & 31), cb = ks * 16 + (lane >> 5) * 8;
        #pragma unroll
        for (int e = 0; e < 8; ++e) {
            float v = W_in[o * 64 + cb + e] * gn_g[cb + e];
            unsigned short h = f2bf(v);
            WP1[idx * 8 + e] = hl ? f2bf(v - bf2f(h)) : h;
        }
    } else if (idx < 3072) {
        int i2 = idx - 2048;
        int lane = i2 & 63, ks = (i2 >> 6) & 3, nf = (i2 >> 8) & 1, hl = i2 >> 9;
        int j = nf * 32 + (lane & 31), ob = ks * 16 + (lane >> 5) * 8;
        #pragma unroll
        for (int e = 0; e < 8; ++e) {
            float v = W_out[j * 64 + ob + e];
            unsigned short h = f2bf(v);
            WP2[i2 * 8 + e] = hl ? f2bf(v - bf2f(h)) : h;
        }
    } else if (idx < 3200) {
        int o = idx - 3072;
        float s = b_in[o];
        for (int c = 0; c < 64; ++c) s += W_in[o * 64 + c] * gn_b[c];
        OFF1[o] = s;
    }
}

// ---------------- lambda tables ----------------
__global__ void k_lam(const float* __restrict__ dt, const float* __restrict__ nu_log,
                      const float* __restrict__ theta_log,
                      float* __restrict__ lr_t, float* __restrict__ li_t, float* __restrict__ gm_t) {
    int idx = blockIdx.x * 256 + threadIdx.x;
    if (idx >= N_ * C_) return;
    int c = idx & 63, n = idx >> 6;
    float dtv = dt[n];
    float decay = expf(-expf(nu_log[c]) * dtv);
    float phase = expf(theta_log[c]) * dtv;
    lr_t[idx] = decay * cosf(phase);
    li_t[idx] = decay * sinf(phase);
    gm_t[idx] = sqrtf(fmaxf(1.f - decay * decay, 1e-6f));
}

// ---------------- x transpose to bf16 plane: xhi[n][pix][ic]  (1024 blocks) ----------------
__global__ __launch_bounds__(256) void k_tr(const float* __restrict__ x,
                                            unsigned short* __restrict__ xhi) {
    __shared__ float t[64][129];
    int blk = blockIdx.x;
    int n = blk >> 5, seg = blk & 31;
    int p0 = seg * 128;
    int b = n >> 4, l = n & 15;
    int tid = threadIdx.x;
    for (int i = 0; i < 32; ++i) {
        int idx = i * 256 + tid;
        int ic = idx >> 7, p = idx & 127;
        t[ic][p] = x[(((size_t)(b * 64 + ic) * 16 + l)) * 4096 + p0 + p];
    }
    __syncthreads();
    for (int it = 0; it < 4; ++it) {
        int chunk = it * 256 + tid;
        int p = chunk >> 3, c0 = (chunk & 7) * 8;
        unsigned short h8[8];
        #pragma unroll
        for (int e = 0; e < 8; ++e) h8[e] = f2bf(t[c0 + e][p]);
        size_t off = ((size_t)(n * 4096 + p0 + p)) * 64 + c0;
        *(uint4*)&xhi[off] = *(uint4*)h8;
    }
}

// ---------------- MFMA implicit-GEMM 7x7 conv (unchanged from r6) ----------------
__global__ __launch_bounds__(256, 2) void k_conv(
    const unsigned short* __restrict__ xhi,
    const unsigned short* __restrict__ WpH,
    const float* __restrict__ b_dc, float* __restrict__ y) {
    __shared__ uint4 halo[3904];
    int tid = threadIdx.x;
    int tile = blockIdx.x;
    int th = tile >> 2, tw = tile & 3;
    int n = blockIdx.y;
    int lane = tid & 63, wid = tid >> 6;
    int dh = (lane >> 4) & 1, dw = lane & 15, kslot = lane >> 5;

    for (int u2 = wid; u2 < 61; u2 += 4) {
        int row = u2 * 8 + (lane >> 3);
        if (row > 483) row = 483;
        int hh = row / 22, ww = row - hh * 22;
        int hs = th * 16 + hh - 3; hs = hs < 0 ? 0 : (hs > 63 ? 63 : hs);
        int wv = (tw * 16 + ww - 3) & 63;
        const uint4* src = (const uint4*)(xhi + ((size_t)n * 4096 + hs * 64 + wv) * 64) + (lane & 7);
        uint4 v = *src;
        *(uint4*)((char*)halo + ((row << 7) + (((lane & 7) ^ (row & 7)) << 4))) = v;
    }
    __syncthreads();

    f32x16 acc[2][2] = {};
    bf16x8 Ba[2][4], Bb[2][4];

#define LOADB(Breg, tap) { \
    const bf16x8* WH = (const bf16x8*)WpH + (size_t)(tap) * 512 + lane; \
    _Pragma("unroll") for (int nf = 0; nf < 2; ++nf) \
        _Pragma("unroll") for (int ks = 0; ks < 4; ++ks) \
            Breg[nf][ks] = WH[(nf * 4 + ks) * 64]; }

#define COMPUTE(khv, kwv, Breg) { \
    bf16x8 A[2][4]; \
    _Pragma("unroll") for (int m = 0; m < 2; ++m) { \
        int rowb = (wid * 4 + 2 * m + dh + (khv)) * 22 + dw + (kwv); \
        _Pragma("unroll") for (int ks = 0; ks < 4; ++ks) { \
            int byt = (rowb << 7) + (((2 * ks + kslot) ^ (rowb & 7)) << 4); \
            A[m][ks] = *(const bf16x8*)((const char*)halo + byt); } } \
    _Pragma("unroll") for (int ks = 0; ks < 4; ++ks) \
        _Pragma("unroll") for (int m = 0; m < 2; ++m) \
            _Pragma("unroll") for (int nf = 0; nf < 2; ++nf) \
                acc[m][nf] = __builtin_amdgcn_mfma_f32_32x32x16_bf16(A[m][ks], Breg[nf][ks], acc[m][nf], 0, 0, 0); }

    LOADB(Ba, 0);
    int kh = 0, kw = 0;
    for (int t = 0; t < 48; t += 2) {
        LOADB(Bb, t + 1);
        COMPUTE(kh, kw, Ba);
        ++kw; if (kw == 7) { kw = 0; ++kh; }
        LOADB(Ba, t + 2);
        COMPUTE(kh, kw, Bb);
        ++kw; if (kw == 7) { kw = 0; ++kh; }
    }
    COMPUTE(kh, kw, Ba);
#undef LOADB
#undef COMPUTE

    int ocl = lane & 31;
    #pragma unroll
    for (int nf = 0; nf < 2; ++nf) {
        float bv = b_dc[nf * 32 + ocl];
        #pragma unroll
        for (int m = 0; m < 2; ++m) {
            #pragma unroll
            for (int j = 0; j < 16; ++j) {
                int r = (j & 3) + 8 * (j >> 2) + 4 * (lane >> 5);
                int h = th * 16 + wid * 4 + 2 * m + (r >> 4);
                int w = tw * 16 + (r & 15);
                y[((size_t)n * 4096 + h * 64 + w) * 64 + nf * 32 + ocl] = acc[m][nf][j] + bv;
            }
        }
    }
}

// ---------------- GroupNorm partial sums (unchanged) ----------------
__global__ __launch_bounds__(256) void k_gnstats(const float* __restrict__ y,
                                                 float* __restrict__ part) {
    int bid = blockIdx.x;
    int n = bid >> 3, chunk = bid & 7;
    int tid = threadIdx.x;
    int c4 = tid & 15, pl = tid >> 4;
    int g = c4 >> 2;
    float s = 0.f, s2 = 0.f;
    for (int i = 0; i < 32; ++i) {
        int p = chunk * 512 + i * 16 + pl;
        float4 v = *(const float4*)&y[((size_t)n * 4096 + p) * 64 + c4 * 4];
        s  += v.x + v.y + v.z + v.w;
        s2 += v.x * v.x + v.y * v.y + v.z * v.z + v.w * v.w;
    }
    __shared__ float rs[256], rq[256];
    int slot = g * 64 + pl * 4 + (c4 & 3);
    rs[slot] = s; rq[slot] = s2;
    __syncthreads();
    for (int off = 32; off >= 1; off >>= 1) {
        int g2 = tid >> 6, k = tid & 63;
        if (k < off) {
            rs[g2 * 64 + k] += rs[g2 * 64 + k + off];
            rq[g2 * 64 + k] += rq[g2 * 64 + k + off];
        }
        __syncthreads();
    }
    if (tid < 4) {
        part[bid * 8 + tid * 2]     = rs[tid * 64];
        part[bid * 8 + tid * 2 + 1] = rq[tid * 64];
    }
}

// ---------------- MFMA pointwise: GN-fold + W_in + GLU + W_out + residual ----------------
// 512 blocks x 4 waves; each wave owns 64 pixels, wave-private 8704B LDS (no barriers).
__global__ __launch_bounds__(256, 1) void k_pw(
    const float* __restrict__ y, const float* __restrict__ part,
    const unsigned short* __restrict__ WP1, const unsigned short* __restrict__ WP2,
    const float* __restrict__ OFF1, const float* __restrict__ b_out,
    const float* __restrict__ x, float* __restrict__ u) {
    __shared__ __align__(16) char lds[4 * 8704];
    int tid = threadIdx.x, lane = tid & 63, wid = tid >> 6;
    int blk = blockIdx.x;
    int n = blk >> 4, pgrp = blk & 15;
    int b = n >> 4, l = n & 15;
    int ocl = lane & 31, hi5 = lane >> 5;
    int pixw = pgrp * 256 + wid * 64;
    char* myl = lds + wid * 8704;

    // group stats
    float mu[4], rsd[4];
    #pragma unroll
    for (int g = 0; g < 4; ++g) {
        float sm = 0.f, sq = 0.f;
        #pragma unroll
        for (int ch = 0; ch < 8; ++ch) {
            sm += part[(n * 8 + ch) * 8 + g * 2];
            sq += part[(n * 8 + ch) * 8 + g * 2 + 1];
        }
        float mean = sm * (1.f / 65536.f);
        float var  = sq * (1.f / 65536.f) - mean * mean;
        mu[g] = mean;
        rsd[g] = rsqrtf(var + 1e-5f);
    }

    const bf16x8* W1 = (const bf16x8*)WP1;
    const bf16x8* W2 = (const bf16x8*)WP2;

    for (int mf = 0; mf < 2; ++mf) {
        int prow = pixw + mf * 32 + ocl;

        // ---- A1 fragments from f32 y, GN pixel-affine applied, bf16
        bf16x8 A1[4];
        #pragma unroll
        for (int ks = 0; ks < 4; ++ks) {
            const float* yb = &y[(size_t)(n * 4096 + prow) * 64 + ks * 16 + hi5 * 8];
            float4 va = *(const float4*)yb;
            float4 vb = *(const float4*)(yb + 4);
            float m = mu[ks], r = rsd[ks];
            bf16x8 a;
            a[0] = (short)f2bf((va.x - m) * r); a[1] = (short)f2bf((va.y - m) * r);
            a[2] = (short)f2bf((va.z - m) * r); a[3] = (short)f2bf((va.w - m) * r);
            a[4] = (short)f2bf((vb.x - m) * r); a[5] = (short)f2bf((vb.y - m) * r);
            a[6] = (short)f2bf((vb.z - m) * r); a[7] = (short)f2bf((vb.w - m) * r);
            A1[ks] = a;
        }

        // ---- GEMM1: acc1[nf] (nf0,1 = x1; nf2,3 = x2), init with OFF1
        f32x16 acc1[4];
        #pragma unroll
        for (int nf = 0; nf < 4; ++nf) {
            float o0 = OFF1[nf * 32 + ocl];
            #pragma unroll
            for (int j = 0; j < 16; ++j) acc1[nf][j] = o0;
        }
        #pragma unroll
        for (int ks = 0; ks < 4; ++ks)
            #pragma unroll
            for (int nf = 0; nf < 4; ++nf) {
                bf16x8 bh = W1[nf * 256 + ks * 64 + lane];
                bf16x8 bl = W1[1024 + nf * 256 + ks * 64 + lane];
                acc1[nf] = __builtin_amdgcn_mfma_f32_32x32x16_bf16(A1[ks], bh, acc1[nf], 0, 0, 0);
                acc1[nf] = __builtin_amdgcn_mfma_f32_32x32x16_bf16(A1[ks], bl, acc1[nf], 0, 0, 0);
            }

        // ---- GLU -> zpan bf16 [32 rows][68]
        unsigned short* zp = (unsigned short*)myl;
        #pragma unroll
        for (int nf = 0; nf < 2; ++nf)
            #pragma unroll
            for (int j = 0; j < 16; ++j) {
                int r = (j & 3) + 8 * (j >> 2) + 4 * hi5;
                float x1 = acc1[nf][j], x2 = acc1[nf + 2][j];
                float z = x1 / (1.f + __expf(-x2));
                zp[r * 68 + nf * 32 + ocl] = f2bf(z);
            }
        asm volatile("s_waitcnt lgkmcnt(0)" ::: "memory");
        __builtin_amdgcn_sched_barrier(0);

        // ---- A2 fragments from zpan
        bf16x8 A2[4];
        #pragma unroll
        for (int ks = 0; ks < 4; ++ks)
            A2[ks] = *(const bf16x8*)(myl + ocl * 136 + ks * 32 + hi5 * 16);

        // ---- GEMM2
        f32x16 acc2[2];
        #pragma unroll
        for (int nf = 0; nf < 2; ++nf)
            #pragma unroll
            for (int j = 0; j < 16; ++j) acc2[nf][j] = 0.f;
        #pragma unroll
        for (int ks = 0; ks < 4; ++ks)
            #pragma unroll
            for (int nf = 0; nf < 2; ++nf) {
                bf16x8 bh = W2[nf * 256 + ks * 64 + lane];
                bf16x8 bl = W2[512 + nf * 256 + ks * 64 + lane];
                acc2[nf] = __builtin_amdgcn_mfma_f32_32x32x16_bf16(A2[ks], bh, acc2[nf], 0, 0, 0);
                acc2[nf] = __builtin_amdgcn_mfma_f32_32x32x16_bf16(A2[ks], bl, acc2[nf], 0, 0, 0);
            }
        asm volatile("s_waitcnt lgkmcnt(0)" ::: "memory");
        __builtin_amdgcn_sched_barrier(0);

        // ---- acc2 -> upan f32 [32][68] (overlays zpan)
        float* up = (float*)myl;
        #pragma unroll
        for (int nf = 0; nf < 2; ++nf)
            #pragma unroll
            for (int j = 0; j < 16; ++j) {
                int r = (j & 3) + 8 * (j >> 2) + 4 * hi5;
                up[r * 68 + nf * 32 + ocl] = acc2[nf][j];
            }
        asm volatile("s_waitcnt lgkmcnt(0)" ::: "memory");
        __builtin_amdgcn_sched_barrier(0);

        // ---- per-pixel pass: lane row = ocl, cols hi5*32..+32: add b_out + x residual
        {
            float* rowp = up + ocl * 68 + hi5 * 32;
            float vrow[32];
            #pragma unroll
            for (int c4 = 0; c4 < 8; ++c4) {
                float4 v = *(const float4*)&rowp[c4 * 4];
                vrow[c4 * 4 + 0] = v.x; vrow[c4 * 4 + 1] = v.y;
                vrow[c4 * 4 + 2] = v.z; vrow[c4 * 4 + 3] = v.w;
            }
            int pixg = pixw + mf * 32 + ocl;
            #pragma unroll
            for (int k = 0; k < 32; ++k) {
                int c = hi5 * 32 + k;
                vrow[k] += b_out[c] + x[((size_t)(b * 64 + c) * 16 + l) * 4096 + pixg];
            }
            #pragma unroll
            for (int c4 = 0; c4 < 8; ++c4) {
                float4 v;
                v.x = vrow[c4 * 4 + 0]; v.y = vrow[c4 * 4 + 1];
                v.z = vrow[c4 * 4 + 2]; v.w = vrow[c4 * 4 + 3];
                *(float4*)&rowp[c4 * 4] = v;
            }
        }
        asm volatile("s_waitcnt lgkmcnt(0)" ::: "memory");
        __builtin_amdgcn_sched_barrier(0);

        // ---- coalesced u store
        #pragma unroll
        for (int i = 0; i < 8; ++i) {
            int e = i * 64 + lane;
            int row = e >> 4, c4 = e & 15;
            float4 v = *(const float4*)&up[row * 68 + c4 * 4];
            *(float4*)&u[((size_t)(n * 4096 + pixw + mf * 32 + row)) * 64 + c4 * 4] = v;
        }
        asm volatile("s_waitcnt lgkmcnt(0)" ::: "memory");
        __builtin_amdgcn_sched_barrier(0);
    }
}

// ---------------- LRU scan (unchanged) ----------------
__global__ __launch_bounds__(256) void k_scan(
    const float* __restrict__ u, const float* __restrict__ lr_t,
    const float* __restrict__ li_t, const float* __restrict__ gm_t,
    const float* __restrict__ c_re, const float* __restrict__ c_im,
    const float* __restrict__ d_skip, float* __restrict__ out) {
    __shared__ float us[16][68];
    int tid = threadIdx.x;
    int bid = blockIdx.x;
    int b = bid >> 8, h = (bid >> 2) & 63, wq = bid & 3;
    int c4 = tid & 15, p = tid >> 4;
    int w = wq * 16 + p;
    float4 cr4 = *(const float4*)&c_re[c4 * 4];
    float4 ci4 = *(const float4*)&c_im[c4 * 4];
    float4 ds4 = *(const float4*)&d_skip[c4 * 4];
    float hr[4] = {}, hi[4] = {};
    int wp = tid & 15, cc = tid >> 4;
    for (int l = 0; l < 16; ++l) {
        int n = b * 16 + l;
        float4 uv = *(const float4*)&u[((size_t)(n * 4096 + h * 64 + w)) * 64 + c4 * 4];
        float4 lr4 = *(const float4*)&lr_t[n * 64 + c4 * 4];
        float4 li4 = *(const float4*)&li_t[n * 64 + c4 * 4];
        float4 gm4 = *(const float4*)&gm_t[n * 64 + c4 * 4];
        float yv[4];
        {
            float ut = uv.x, lr = lr4.x, li = li4.x;
            float nr = lr * hr[0] - li * hi[0] + gm4.x * ut;
            float ni = li * hr[0] + lr * hi[0];
            yv[0] = cr4.x * nr + ci4.x * ni + ds4.x * ut; hr[0] = nr; hi[0] = ni;
        }
        {
            float ut = uv.y, lr = lr4.y, li = li4.y;
            float nr = lr * hr[1] - li * hi[1] + gm4.y * ut;
            float ni = li * hr[1] + lr * hi[1];
            yv[1] = cr4.y * nr + ci4.y * ni + ds4.y * ut; hr[1] = nr; hi[1] = ni;
        }
        {
            float ut = uv.z, lr = lr4.z, li = li4.z;
            float nr = lr * hr[2] - li * hi[2] + gm4.z * ut;
            float ni = li * hr[2] + lr * hi[2];
            yv[2] = cr4.z * nr + ci4.z * ni + ds4.z * ut; hr[2] = nr; hi[2] = ni;
        }
        {
            float ut = uv.w, lr = lr4.w, li = li4.w;
            float nr = lr * hr[3] - li * hi[3] + gm4.w * ut;
            float ni = li * hr[3] + lr * hi[3];
            yv[3] = cr4.w * nr + ci4.w * ni + ds4.w * ut; hr[3] = nr; hi[3] = ni;
        }
        *(float4*)&us[p][c4 * 4] = *(float4*)yv;
        __syncthreads();
        #pragma unroll
        for (int j = 0; j < 4; ++j) {
            int c = cc * 4 + j;
            out[((size_t)(b * 64 + c) * 16 + l) * 4096 + h * 64 + wq * 16 + wp] = us[wp][c];
        }
        __syncthreads();
    }
}

extern "C" void kernel_launch(void* const* d_in, const int* in_sizes, int n_in,
                              void* d_out, int out_size, void* d_ws, size_t ws_size,
                              hipStream_t stream) {
    const float* x        = (const float*)d_in[0];
    const float* dt       = (const float*)d_in[1];
    const float* W_sp     = (const float*)d_in[2];
    const float* W_dc     = (const float*)d_in[3];
    const float* b_dc     = (const float*)d_in[4];
    const float* gn_g     = (const float*)d_in[5];
    const float* gn_b     = (const float*)d_in[6];
    const float* W_in     = (const float*)d_in[7];
    const float* b_in     = (const float*)d_in[8];
    const float* W_out    = (const float*)d_in[9];
    const float* b_out    = (const float*)d_in[10];
    const float* nu_log   = (const float*)d_in[11];
    const float* theta_log= (const float*)d_in[12];
    const float* c_re     = (const float*)d_in[13];
    const float* c_im     = (const float*)d_in[14];
    const float* d_skip   = (const float*)d_in[15];

    char* ws = (char*)d_ws;
    unsigned short* WpH  = (unsigned short*)(ws + BY_WPH);
    unsigned short* WP1  = (unsigned short*)(ws + BY_WP1);
    unsigned short* WP2  = (unsigned short*)(ws + BY_WP2);
    float* OFF1   = (float*)(ws + BY_OFF1);
    float* lr_t   = (float*)(ws + BY_LR);
    float* li_t   = (float*)(ws + BY_LI);
    float* gm_t   = (float*)(ws + BY_GM);
    float* part   = (float*)(ws + BY_PART);
    unsigned short* xhi = (unsigned short*)(ws + BY_XHI);
    float* u      = (float*)(ws + BY_U);
    float* y      = (float*)d_out;     // y lives in d_out until k_pw consumes it
    float* out    = (float*)d_out;

    hipLaunchKernelGGL(k_pack,    dim3(98),        dim3(256), 0, stream, W_sp, W_dc, WpH);
    hipLaunchKernelGGL(k_prep,    dim3(13),        dim3(256), 0, stream, W_in, b_in, W_out,
                       gn_g, gn_b, WP1, WP2, OFF1);
    hipLaunchKernelGGL(k_lam,     dim3(8),         dim3(256), 0, stream, dt, nu_log, theta_log, lr_t, li_t, gm_t);
    hipLaunchKernelGGL(k_tr,      dim3(1024),      dim3(256), 0, stream, x, xhi);
    hipLaunchKernelGGL(k_conv,    dim3(16, 32),    dim3(256), 0, stream, xhi, WpH, b_dc, y);
    hipLaunchKernelGGL(k_gnstats, dim3(256),       dim3(256), 0, stream, y, part);
    hipLaunchKernelGGL(k_pw,      dim3(512),       dim3(256), 0, stream, y, part, WP1, WP2,
                       OFF1, b_out, x, u);
    hipLaunchKernelGGL(k_scan,    dim3(512),       dim3(256), 0, stream, u, lr_t, li_t, gm_t,
                       c_re, c_im, d_skip, out);
}

// Round 8
// 143.632 us; speedup vs baseline: 3.0499x; 1.0828x over previous
//
#include <hip/hip_runtime.h>
#include <hip/hip_bf16.h>

typedef short bf16x8 __attribute__((ext_vector_type(8)));
typedef float f32x16 __attribute__((ext_vector_type(16)));

#define B_ 2
#define C_ 64
#define L_ 16
#define N_ 32
#define HW_ 4096

// ---- ws byte layout ----
#define BY_WPH  0u          // conv packed weights: 25088 frags * 16B = 401408
#define BY_WP1  401408u     // W_in' B-frags hi/lo: 2*16*64*16B = 32768
#define BY_WP2  434176u     // W_out B-frags hi/lo: 2*8*64*16B = 16384
#define BY_OFF1 450560u     // 128 f32
#define BY_LR   451072u
#define BY_LI   459264u
#define BY_GM   467456u
#define BY_PART 475648u     // conv per-block gn partials: 32*16*8 f32 = 16384
#define BY_XHI  524288u     // x bf16 plane [n][pix][ic] = 16777216 (dead after conv)
#define BY_U    524288u     // u f32 [n][pix][c] = 33554432 (aliases XHI)

__device__ __forceinline__ unsigned short f2bf(float v) {
    unsigned int u = __float_as_uint(v);
    unsigned int r = u + 0x7FFFu + ((u >> 16) & 1u);
    return (unsigned short)(r >> 16);
}
__device__ __forceinline__ float bf2f(unsigned short s) {
    return __uint_as_float(((unsigned int)s) << 16);
}

// ---------------- pack conv W_eff = W_dc @ W_sp into B-fragment layout ----------------
__global__ void k_pack(const float* __restrict__ W_sp, const float* __restrict__ W_dc,
                       unsigned short* __restrict__ WpH) {
    int idx = blockIdx.x * 256 + threadIdx.x;
    if (idx >= 49 * 512) return;
    int lane = idx & 63;
    int ks   = (idx >> 6) & 3;
    int nf   = (idx >> 8) & 1;
    int tap  = idx >> 9;
    int oc   = nf * 32 + (lane & 31);
    int icb  = ks * 16 + (lane >> 5) * 8;
    unsigned short h8[8];
    #pragma unroll
    for (int e = 0; e < 8; ++e) {
        int ic = icb + e;
        float s = 0.f;
        for (int c = 0; c < 64; ++c)
            s += W_dc[oc * 64 + c] * W_sp[(c * 64 + ic) * 49 + tap];
        h8[e] = f2bf(s);
    }
    #pragma unroll
    for (int e = 0; e < 8; ++e) WpH[idx * 8 + e] = h8[e];
}

// ---------------- pack pointwise weights: W_in*gn_g (hi/lo), W_out (hi/lo), off1 ----------------
__global__ void k_prep(const float* __restrict__ W_in, const float* __restrict__ b_in,
                       const float* __restrict__ W_out,
                       const float* __restrict__ gn_g, const float* __restrict__ gn_b,
                       unsigned short* __restrict__ WP1, unsigned short* __restrict__ WP2,
                       float* __restrict__ OFF1) {
    int idx = blockIdx.x * 256 + threadIdx.x;
    if (idx < 2048) {
        int lane = idx & 63, ks = (idx >> 6) & 3, nf = (idx >> 8) & 3, hl = idx >> 10;
        int o = nf * 32 + (lane & 31), cb = ks * 16 + (lane >> 5) * 8;
        #pragma unroll
        for (int e = 0; e < 8; ++e) {
            float v = W_in[o * 64 + cb + e] * gn_g[cb + e];
            unsigned short h = f2bf(v);
            WP1[idx * 8 + e] = hl ? f2bf(v - bf2f(h)) : h;
        }
    } else if (idx < 3072) {
        int i2 = idx - 2048;
        int lane = i2 & 63, ks = (i2 >> 6) & 3, nf = (i2 >> 8) & 1, hl = i2 >> 9;
        int j = nf * 32 + (lane & 31), ob = ks * 16 + (lane >> 5) * 8;
        #pragma unroll
        for (int e = 0; e < 8; ++e) {
            float v = W_out[j * 64 + ob + e];
            unsigned short h = f2bf(v);
            WP2[i2 * 8 + e] = hl ? f2bf(v - bf2f(h)) : h;
        }
    } else if (idx < 3200) {
        int o = idx - 3072;
        float s = b_in[o];
        for (int c = 0; c < 64; ++c) s += W_in[o * 64 + c] * gn_b[c];
        OFF1[o] = s;
    }
}

// ---------------- lambda tables ----------------
__global__ void k_lam(const float* __restrict__ dt, const float* __restrict__ nu_log,
                      const float* __restrict__ theta_log,
                      float* __restrict__ lr_t, float* __restrict__ li_t, float* __restrict__ gm_t) {
    int idx = blockIdx.x * 256 + threadIdx.x;
    if (idx >= N_ * C_) return;
    int c = idx & 63, n = idx >> 6;
    float dtv = dt[n];
    float decay = expf(-expf(nu_log[c]) * dtv);
    float phase = expf(theta_log[c]) * dtv;
    lr_t[idx] = decay * cosf(phase);
    li_t[idx] = decay * sinf(phase);
    gm_t[idx] = sqrtf(fmaxf(1.f - decay * decay, 1e-6f));
}

// ---------------- x transpose to bf16 plane: xhi[n][pix][ic]  (1024 blocks) ----------------
__global__ __launch_bounds__(256) void k_tr(const float* __restrict__ x,
                                            unsigned short* __restrict__ xhi) {
    __shared__ float t[64][129];
    int blk = blockIdx.x;
    int n = blk >> 5, seg = blk & 31;
    int p0 = seg * 128;
    int b = n >> 4, l = n & 15;
    int tid = threadIdx.x;
    for (int i = 0; i < 32; ++i) {
        int idx = i * 256 + tid;
        int ic = idx >> 7, p = idx & 127;
        t[ic][p] = x[(((size_t)(b * 64 + ic) * 16 + l)) * 4096 + p0 + p];
    }
    __syncthreads();
    for (int it = 0; it < 4; ++it) {
        int chunk = it * 256 + tid;
        int p = chunk >> 3, c0 = (chunk & 7) * 8;
        unsigned short h8[8];
        #pragma unroll
        for (int e = 0; e < 8; ++e) h8[e] = f2bf(t[c0 + e][p]);
        size_t off = ((size_t)(n * 4096 + p0 + p)) * 64 + c0;
        *(uint4*)&xhi[off] = *(uint4*)h8;
    }
}

// ---------------- MFMA implicit-GEMM 7x7 conv, A+B software pipeline, fused GN partials ----------------
__global__ __launch_bounds__(256, 2) void k_conv(
    const unsigned short* __restrict__ xhi,
    const unsigned short* __restrict__ WpH,
    const float* __restrict__ b_dc, float* __restrict__ y,
    float* __restrict__ part) {
    __shared__ uint4 halo[3904];
    __shared__ float ps[4][8], pq[4][8];
    int tid = threadIdx.x;
    int tile = blockIdx.x;
    int th = tile >> 2, tw = tile & 3;
    int n = blockIdx.y;
    int lane = tid & 63, wid = tid >> 6;
    int dh = (lane >> 4) & 1, dw = lane & 15, kslot = lane >> 5;

    for (int u2 = wid; u2 < 61; u2 += 4) {
        int row = u2 * 8 + (lane >> 3);
        if (row > 483) row = 483;
        int hh = row / 22, ww = row - hh * 22;
        int hs = th * 16 + hh - 3; hs = hs < 0 ? 0 : (hs > 63 ? 63 : hs);
        int wv = (tw * 16 + ww - 3) & 63;
        const uint4* src = (const uint4*)(xhi + ((size_t)n * 4096 + hs * 64 + wv) * 64) + (lane & 7);
        uint4 v = *src;
        *(uint4*)((char*)halo + ((row << 7) + (((lane & 7) ^ (row & 7)) << 4))) = v;
    }
    __syncthreads();

    f32x16 acc[2][2] = {};
    bf16x8 Aa[2][4], Ab[2][4], Ba[2][4], Bb[2][4];

#define LOADA(Areg, khv, kwv) { \
    _Pragma("unroll") for (int m = 0; m < 2; ++m) { \
        int rowb = (wid * 4 + 2 * m + dh + (khv)) * 22 + dw + (kwv); \
        _Pragma("unroll") for (int ks = 0; ks < 4; ++ks) { \
            int byt = (rowb << 7) + (((2 * ks + kslot) ^ (rowb & 7)) << 4); \
            Areg[m][ks] = *(const bf16x8*)((const char*)halo + byt); } } }

#define LOADB(Breg, tap) { \
    const bf16x8* WH = (const bf16x8*)WpH + (size_t)(tap) * 512 + lane; \
    _Pragma("unroll") for (int nf = 0; nf < 2; ++nf) \
        _Pragma("unroll") for (int ks = 0; ks < 4; ++ks) \
            Breg[nf][ks] = WH[(nf * 4 + ks) * 64]; }

#define MFMA_ALL(Areg, Breg) { \
    _Pragma("unroll") for (int ks = 0; ks < 4; ++ks) \
        _Pragma("unroll") for (int m = 0; m < 2; ++m) \
            _Pragma("unroll") for (int nf = 0; nf < 2; ++nf) \
                acc[m][nf] = __builtin_amdgcn_mfma_f32_32x32x16_bf16(Areg[m][ks], Breg[nf][ks], acc[m][nf], 0, 0, 0); }

    int kh = 0, kw = 0;
    LOADA(Aa, 0, 0); LOADB(Ba, 0);
    for (int t = 0; t < 48; t += 2) {
        ++kw; if (kw == 7) { kw = 0; ++kh; }        // tap t+1
        LOADA(Ab, kh, kw); LOADB(Bb, t + 1);
        MFMA_ALL(Aa, Ba);                            // tap t
        ++kw; if (kw == 7) { kw = 0; ++kh; }        // tap t+2
        LOADA(Aa, kh, kw); LOADB(Ba, t + 2);
        MFMA_ALL(Ab, Bb);                            // tap t+1
    }
    MFMA_ALL(Aa, Ba);                                // tap 48
#undef LOADA
#undef LOADB
#undef MFMA_ALL

    // epilogue: store y + per-block GN partial sums
    int ocl = lane & 31;
    float sg[2], qg[2];
    #pragma unroll
    for (int nf = 0; nf < 2; ++nf) {
        float bv = b_dc[nf * 32 + ocl];
        float ss = 0.f, qq = 0.f;
        #pragma unroll
        for (int m = 0; m < 2; ++m) {
            #pragma unroll
            for (int j = 0; j < 16; ++j) {
                int r = (j & 3) + 8 * (j >> 2) + 4 * (lane >> 5);
                int h = th * 16 + wid * 4 + 2 * m + (r >> 4);
                int w = tw * 16 + (r & 15);
                float v = acc[m][nf][j] + bv;
                y[((size_t)n * 4096 + h * 64 + w) * 64 + nf * 32 + ocl] = v;
                ss += v; qq += v * v;
            }
        }
        sg[nf] = ss; qg[nf] = qq;
    }
    #pragma unroll
    for (int off = 1; off < 16; off <<= 1) {
        sg[0] += __shfl_xor(sg[0], off);
        qg[0] += __shfl_xor(qg[0], off);
        sg[1] += __shfl_xor(sg[1], off);
        qg[1] += __shfl_xor(qg[1], off);
    }
    if ((lane & 15) == 0) {
        int cl = lane >> 4;
        int g0 = cl & 1, slot = wid * 2 + (cl >> 1);
        ps[g0][slot] = sg[0];     pq[g0][slot] = qg[0];
        ps[2 + g0][slot] = sg[1]; pq[2 + g0][slot] = qg[1];
    }
    __syncthreads();
    if (tid < 4) {
        float ss = 0.f, qq = 0.f;
        #pragma unroll
        for (int k2 = 0; k2 < 8; ++k2) { ss += ps[tid][k2]; qq += pq[tid][k2]; }
        part[((size_t)(n * 16 + tile)) * 8 + tid * 2]     = ss;
        part[((size_t)(n * 16 + tile)) * 8 + tid * 2 + 1] = qq;
    }
}

// ---------------- MFMA pointwise: GN-fold + W_in + GLU + W_out + residual ----------------
__global__ __launch_bounds__(256, 1) void k_pw(
    const float* __restrict__ y, const float* __restrict__ part,
    const unsigned short* __restrict__ WP1, const unsigned short* __restrict__ WP2,
    const float* __restrict__ OFF1, const float* __restrict__ b_out,
    const float* __restrict__ x, float* __restrict__ u) {
    __shared__ __align__(16) char lds[4 * 8704];
    int tid = threadIdx.x, lane = tid & 63, wid = tid >> 6;
    int blk = blockIdx.x;
    int n = blk >> 4, pgrp = blk & 15;
    int b = n >> 4, l = n & 15;
    int ocl = lane & 31, hi5 = lane >> 5;
    int pixw = pgrp * 256 + wid * 64;
    char* myl = lds + wid * 8704;

    float mu[4], rsd[4];
    #pragma unroll
    for (int g = 0; g < 4; ++g) {
        float sm = 0.f, sq = 0.f;
        #pragma unroll
        for (int ch = 0; ch < 16; ++ch) {
            sm += part[(n * 16 + ch) * 8 + g * 2];
            sq += part[(n * 16 + ch) * 8 + g * 2 + 1];
        }
        float mean = sm * (1.f / 65536.f);
        float var  = sq * (1.f / 65536.f) - mean * mean;
        mu[g] = mean;
        rsd[g] = rsqrtf(var + 1e-5f);
    }

    const bf16x8* W1 = (const bf16x8*)WP1;
    const bf16x8* W2 = (const bf16x8*)WP2;

    for (int mf = 0; mf < 2; ++mf) {
        int prow = pixw + mf * 32 + ocl;

        bf16x8 A1[4];
        #pragma unroll
        for (int ks = 0; ks < 4; ++ks) {
            const float* yb = &y[(size_t)(n * 4096 + prow) * 64 + ks * 16 + hi5 * 8];
            float4 va = *(const float4*)yb;
            float4 vb = *(const float4*)(yb + 4);
            float m = mu[ks], r = rsd[ks];
            bf16x8 a;
            a[0] = (short)f2bf((va.x - m) * r); a[1] = (short)f2bf((va.y - m) * r);
            a[2] = (short)f2bf((va.z - m) * r); a[3] = (short)f2bf((va.w - m) * r);
            a[4] = (short)f2bf((vb.x - m) * r); a[5] = (short)f2bf((vb.y - m) * r);
            a[6] = (short)f2bf((vb.z - m) * r); a[7] = (short)f2bf((vb.w - m) * r);
            A1[ks] = a;
        }

        f32x16 acc1[4];
        #pragma unroll
        for (int nf = 0; nf < 4; ++nf) {
            float o0 = OFF1[nf * 32 + ocl];
            #pragma unroll
            for (int j = 0; j < 16; ++j) acc1[nf][j] = o0;
        }
        #pragma unroll
        for (int ks = 0; ks < 4; ++ks)
            #pragma unroll
            for (int nf = 0; nf < 4; ++nf) {
                bf16x8 bh = W1[nf * 256 + ks * 64 + lane];
                bf16x8 bl = W1[1024 + nf * 256 + ks * 64 + lane];
                acc1[nf] = __builtin_amdgcn_mfma_f32_32x32x16_bf16(A1[ks], bh, acc1[nf], 0, 0, 0);
                acc1[nf] = __builtin_amdgcn_mfma_f32_32x32x16_bf16(A1[ks], bl, acc1[nf], 0, 0, 0);
            }

        unsigned short* zp = (unsigned short*)myl;
        #pragma unroll
        for (int nf = 0; nf < 2; ++nf)
            #pragma unroll
            for (int j = 0; j < 16; ++j) {
                int r = (j & 3) + 8 * (j >> 2) + 4 * hi5;
                float x1 = acc1[nf][j], x2 = acc1[nf + 2][j];
                float z = x1 / (1.f + __expf(-x2));
                zp[r * 68 + nf * 32 + ocl] = f2bf(z);
            }
        asm volatile("s_waitcnt lgkmcnt(0)" ::: "memory");
        __builtin_amdgcn_sched_barrier(0);

        bf16x8 A2[4];
        #pragma unroll
        for (int ks = 0; ks < 4; ++ks)
            A2[ks] = *(const bf16x8*)(myl + ocl * 136 + ks * 32 + hi5 * 16);

        f32x16 acc2[2];
        #pragma unroll
        for (int nf = 0; nf < 2; ++nf)
            #pragma unroll
            for (int j = 0; j < 16; ++j) acc2[nf][j] = 0.f;
        #pragma unroll
        for (int ks = 0; ks < 4; ++ks)
            #pragma unroll
            for (int nf = 0; nf < 2; ++nf) {
                bf16x8 bh = W2[nf * 256 + ks * 64 + lane];
                bf16x8 bl = W2[512 + nf * 256 + ks * 64 + lane];
                acc2[nf] = __builtin_amdgcn_mfma_f32_32x32x16_bf16(A2[ks], bh, acc2[nf], 0, 0, 0);
                acc2[nf] = __builtin_amdgcn_mfma_f32_32x32x16_bf16(A2[ks], bl, acc2[nf], 0, 0, 0);
            }
        asm volatile("s_waitcnt lgkmcnt(0)" ::: "memory");
        __builtin_amdgcn_sched_barrier(0);

        float* up = (float*)myl;
        #pragma unroll
        for (int nf = 0; nf < 2; ++nf)
            #pragma unroll
            for (int j = 0; j < 16; ++j) {
                int r = (j & 3) + 8 * (j >> 2) + 4 * hi5;
                up[r * 68 + nf * 32 + ocl] = acc2[nf][j];
            }
        asm volatile("s_waitcnt lgkmcnt(0)" ::: "memory");
        __builtin_amdgcn_sched_barrier(0);

        {
            float* rowp = up + ocl * 68 + hi5 * 32;
            float vrow[32];
            #pragma unroll
            for (int c4 = 0; c4 < 8; ++c4) {
                float4 v = *(const float4*)&rowp[c4 * 4];
                vrow[c4 * 4 + 0] = v.x; vrow[c4 * 4 + 1] = v.y;
                vrow[c4 * 4 + 2] = v.z; vrow[c4 * 4 + 3] = v.w;
            }
            int pixg = pixw + mf * 32 + ocl;
            #pragma unroll
            for (int k = 0; k < 32; ++k) {
                int c = hi5 * 32 + k;
                vrow[k] += b_out[c] + x[((size_t)(b * 64 + c) * 16 + l) * 4096 + pixg];
            }
            #pragma unroll
            for (int c4 = 0; c4 < 8; ++c4) {
                float4 v;
                v.x = vrow[c4 * 4 + 0]; v.y = vrow[c4 * 4 + 1];
                v.z = vrow[c4 * 4 + 2]; v.w = vrow[c4 * 4 + 3];
                *(float4*)&rowp[c4 * 4] = v;
            }
        }
        asm volatile("s_waitcnt lgkmcnt(0)" ::: "memory");
        __builtin_amdgcn_sched_barrier(0);

        #pragma unroll
        for (int i = 0; i < 8; ++i) {
            int e = i * 64 + lane;
            int row = e >> 4, c4 = e & 15;
            float4 v = *(const float4*)&up[row * 68 + c4 * 4];
            *(float4*)&u[((size_t)(n * 4096 + pixw + mf * 32 + row)) * 64 + c4 * 4] = v;
        }
        asm volatile("s_waitcnt lgkmcnt(0)" ::: "memory");
        __builtin_amdgcn_sched_barrier(0);
    }
}

// ---------------- LRU scan ----------------
__global__ __launch_bounds__(256) void k_scan(
    const float* __restrict__ u, const float* __restrict__ lr_t,
    const float* __restrict__ li_t, const float* __restrict__ gm_t,
    const float* __restrict__ c_re, const float* __restrict__ c_im,
    const float* __restrict__ d_skip, float* __restrict__ out) {
    __shared__ float us[16][68];
    int tid = threadIdx.x;
    int bid = blockIdx.x;
    int b = bid >> 8, h = (bid >> 2) & 63, wq = bid & 3;
    int c4 = tid & 15, p = tid >> 4;
    int w = wq * 16 + p;
    float4 cr4 = *(const float4*)&c_re[c4 * 4];
    float4 ci4 = *(const float4*)&c_im[c4 * 4];
    float4 ds4 = *(const float4*)&d_skip[c4 * 4];
    float hr[4] = {}, hi[4] = {};
    int wp = tid & 15, cc = tid >> 4;
    for (int l = 0; l < 16; ++l) {
        int n = b * 16 + l;
        float4 uv = *(const float4*)&u[((size_t)(n * 4096 + h * 64 + w)) * 64 + c4 * 4];
        float4 lr4 = *(const float4*)&lr_t[n * 64 + c4 * 4];
        float4 li4 = *(const float4*)&li_t[n * 64 + c4 * 4];
        float4 gm4 = *(const float4*)&gm_t[n * 64 + c4 * 4];
        float yv[4];
        {
            float ut = uv.x, lr = lr4.x, li = li4.x;
            float nr = lr * hr[0] - li * hi[0] + gm4.x * ut;
            float ni = li * hr[0] + lr * hi[0];
            yv[0] = cr4.x * nr + ci4.x * ni + ds4.x * ut; hr[0] = nr; hi[0] = ni;
        }
        {
            float ut = uv.y, lr = lr4.y, li = li4.y;
            float nr = lr * hr[1] - li * hi[1] + gm4.y * ut;
            float ni = li * hr[1] + lr * hi[1];
            yv[1] = cr4.y * nr + ci4.y * ni + ds4.y * ut; hr[1] = nr; hi[1] = ni;
        }
        {
            float ut = uv.z, lr = lr4.z, li = li4.z;
            float nr = lr * hr[2] - li * hi[2] + gm4.z * ut;
            float ni = li * hr[2] + lr * hi[2];
            yv[2] = cr4.z * nr + ci4.z * ni + ds4.z * ut; hr[2] = nr; hi[2] = ni;
        }
        {
            float ut = uv.w, lr = lr4.w, li = li4.w;
            float nr = lr * hr[3] - li * hi[3] + gm4.w * ut;
            float ni = li * hr[3] + lr * hi[3];
            yv[3] = cr4.w * nr + ci4.w * ni + ds4.w * ut; hr[3] = nr; hi[3] = ni;
        }
        *(float4*)&us[p][c4 * 4] = *(float4*)yv;
        __syncthreads();
        #pragma unroll
        for (int j = 0; j < 4; ++j) {
            int c = cc * 4 + j;
            out[((size_t)(b * 64 + c) * 16 + l) * 4096 + h * 64 + wq * 16 + wp] = us[wp][c];
        }
        __syncthreads();
    }
}

extern "C" void kernel_launch(void* const* d_in, const int* in_sizes, int n_in,
                              void* d_out, int out_size, void* d_ws, size_t ws_size,
                              hipStream_t stream) {
    const float* x        = (const float*)d_in[0];
    const float* dt       = (const float*)d_in[1];
    const float* W_sp     = (const float*)d_in[2];
    const float* W_dc     = (const float*)d_in[3];
    const float* b_dc     = (const float*)d_in[4];
    const float* gn_g     = (const float*)d_in[5];
    const float* gn_b     = (const float*)d_in[6];
    const float* W_in     = (const float*)d_in[7];
    const float* b_in     = (const float*)d_in[8];
    const float* W_out    = (const float*)d_in[9];
    const float* b_out    = (const float*)d_in[10];
    const float* nu_log   = (const float*)d_in[11];
    const float* theta_log= (const float*)d_in[12];
    const float* c_re     = (const float*)d_in[13];
    const float* c_im     = (const float*)d_in[14];
    const float* d_skip   = (const float*)d_in[15];

    char* ws = (char*)d_ws;
    unsigned short* WpH  = (unsigned short*)(ws + BY_WPH);
    unsigned short* WP1  = (unsigned short*)(ws + BY_WP1);
    unsigned short* WP2  = (unsigned short*)(ws + BY_WP2);
    float* OFF1   = (float*)(ws + BY_OFF1);
    float* lr_t   = (float*)(ws + BY_LR);
    float* li_t   = (float*)(ws + BY_LI);
    float* gm_t   = (float*)(ws + BY_GM);
    float* part   = (float*)(ws + BY_PART);
    unsigned short* xhi = (unsigned short*)(ws + BY_XHI);
    float* u      = (float*)(ws + BY_U);
    float* y      = (float*)d_out;     // y lives in d_out until k_pw consumes it
    float* out    = (float*)d_out;

    hipLaunchKernelGGL(k_pack,    dim3(98),        dim3(256), 0, stream, W_sp, W_dc, WpH);
    hipLaunchKernelGGL(k_prep,    dim3(13),        dim3(256), 0, stream, W_in, b_in, W_out,
                       gn_g, gn_b, WP1, WP2, OFF1);
    hipLaunchKernelGGL(k_lam,     dim3(8),         dim3(256), 0, stream, dt, nu_log, theta_log, lr_t, li_t, gm_t);
    hipLaunchKernelGGL(k_tr,      dim3(1024),      dim3(256), 0, stream, x, xhi);
    hipLaunchKernelGGL(k_conv,    dim3(16, 32),    dim3(256), 0, stream, xhi, WpH, b_dc, y, part);
    hipLaunchKernelGGL(k_pw,      dim3(512),       dim3(256), 0, stream, y, part, WP1, WP2,
                       OFF1, b_out, x, u);
    hipLaunchKernelGGL(k_scan,    dim3(512),       dim3(256), 0, stream, u, lr_t, li_t, gm_t,
                       c_re, c_im, d_skip, out);
}